// Round 2
// baseline (14916.377 us; speedup 1.0000x reference)
//
#include <hip/hip_runtime.h>
#include <hip/hip_bf16.h>

// ================= problem constants =================
#define B_ 1024
#define T_ 365
#define D_ 24
#define H_ 128
#define NG 32   // batch groups
#define GB 32   // batch rows per group
#define NS 8    // hidden slices (blocks per group)
#define SC 16   // hidden cols per slice

typedef __attribute__((ext_vector_type(8))) short bf16x8;
typedef __attribute__((ext_vector_type(4))) float f32x4;

#define MFMA(a,b,c) __builtin_amdgcn_mfma_f32_16x16x32_bf16((a),(b),(c),0,0,0)

// h exchange arena + sync flags (device globals; re-zeroed by init kernel each launch)
__device__ __align__(16) unsigned short g_hx[2][4][B_][H_];   // 2 MB, bf16
__device__ unsigned int g_flags[NG][3];

__device__ __forceinline__ unsigned short f2b(float f) {
  union { __hip_bfloat16 h; unsigned short u; } cv;
  cv.h = __float2bfloat16(f);
  return cv.u;
}
__device__ __forceinline__ float b2f(unsigned short u) {
  union { float f; unsigned int u32; } cv;
  cv.u32 = ((unsigned int)u) << 16;
  return cv.f;
}
__device__ __forceinline__ float sigmoidf_(float x) { return 1.f / (1.f + __expf(-x)); }
__device__ __forceinline__ float tanhf_(float x) {
  float e = __expf(2.f * x);
  return 1.f - 2.f / (e + 1.f);
}

// ---------------- init: zero exchange + flags ----------------
__global__ void init_exchange() {
  unsigned int ndw = (2u*4u*B_*H_) / 2;   // dwords in g_hx
  unsigned int stride = gridDim.x * blockDim.x;
  unsigned int i0 = blockIdx.x * blockDim.x + threadIdx.x;
  unsigned int* p = (unsigned int*)&g_hx[0][0][0][0];
  for (unsigned int i = i0; i < ndw; i += stride) p[i] = 0;
  if (i0 < NG*3) (&g_flags[0][0])[i0] = 0;
}

// ---------------- params ----------------
struct Params {
  const float* x;
  const float* wih[4];
  const float* whh[4];
  const float* bih[4];
  const float* bhh[4];
  const float* wfc[4];
  const float* bfc[4];
  float* out;     // [B][T][9]
  float* hf[4];   // [B][128]
  float* hT[4];   // [B][T][128]
};

// swizzled LDS weight fill: local rows r in [0,48) -> global row (r>>4)*128 + s*16 + (r&15)
template<int Kd, int Ksrc>
__device__ __forceinline__ void load_w(unsigned short* dst, const float* src, int s, int tid) {
  for (int i = tid; i < 48*Kd; i += 256) {
    int r = i / Kd, k = i % Kd;
    float v = 0.f;
    if (k < Ksrc) v = src[((r>>4)*H_ + s*SC + (r&15)) * Ksrc + k];
    dst[r*Kd + (((k>>3) ^ (r&7)) << 3) + (k&7)] = f2b(v);
  }
}

__device__ __forceinline__ bf16x8 wfrag(const unsigned short* base, int r, int k, int Kd) {
  return *(const bf16x8*)(base + r*Kd + (((k>>3) ^ (r&7)) << 3));
}

// group barrier among the NS blocks of batch group g (monotonic counters)
__device__ __forceinline__ void group_sync(int g, int st, unsigned int target) {
  __syncthreads();   // all waves' stores done (each wave drains vmcnt before s_barrier)
  if (threadIdx.x == 0) {
    __builtin_amdgcn_fence(__ATOMIC_RELEASE, "agent");
    __hip_atomic_fetch_add(&g_flags[g][st], 1u, __ATOMIC_RELAXED, __HIP_MEMORY_SCOPE_AGENT);
    unsigned int spins = 0;
    while (__hip_atomic_load(&g_flags[g][st], __ATOMIC_RELAXED, __HIP_MEMORY_SCOPE_AGENT) < target) {
      if (++spins > (1u<<24)) break;   // bounded bail-out (never hang the harness)
    }
    __builtin_amdgcn_fence(__ATOMIC_ACQUIRE, "agent");   // buffer_inv: L1+L2 invalidate
  }
  __syncthreads();
}

// gate nonlinearity + state update + publish
__device__ __forceinline__ void finish_cell(const Params& p, f32x4 R, f32x4 Z, f32x4 I, f32x4 Hh,
    int c, float* hreg, float brz0, float brz1, float bi, float bh,
    int pbn, int g, int m, int khi, int colg, int t) {
#pragma unroll
  for (int q = 0; q < 4; ++q) {
    float r = sigmoidf_(R[q] + brz0);
    float z = sigmoidf_(Z[q] + brz1);
    float n = tanhf_(I[q] + bi + r * (Hh[q] + bh));
    float hnew = (1.f - z) * n + z * hreg[q];
    hreg[q] = hnew;
    int row = g*GB + m*16 + khi*4 + q;
    __hip_atomic_store(&g_hx[pbn][c][row][colg], f2b(hnew),
                       __ATOMIC_RELAXED, __HIP_MEMORY_SCOPE_AGENT);
    p.hT[c][(size_t)row * (T_*H_) + (size_t)t * H_ + colg] = hnew;
  }
}

// FC dots: rows 0..31 across 2 waves (wbase..wbase+1); lane=(row 0..15, kq 0..3)
__device__ __forceinline__ void fc_dots(const Params& p, const float (*wfc_l)[H_], const float* bfc_l,
    int cell, int d0, int nd, int g, int pbn, int t, int wid, int lane, int wbase) {
  int row = (wid - wbase) * 16 + (lane & 15);
  int kq = lane >> 4;
  const unsigned short* hb = &g_hx[pbn][cell][g*GB + row][kq*32];
  float hv[32];
#pragma unroll
  for (int j = 0; j < 4; ++j) {
    bf16x8 v = *(const bf16x8*)(hb + j*8);
#pragma unroll
    for (int e = 0; e < 8; ++e) hv[j*8+e] = b2f((unsigned short)v[e]);
  }
  for (int d = 0; d < nd; ++d) {
    const float* wr = wfc_l[d0 + d];
    float acc = 0.f;
#pragma unroll
    for (int j = 0; j < 32; ++j) acc += hv[j] * wr[kq*32 + j];
    acc += __shfl_xor(acc, 16);
    acc += __shfl_xor(acc, 32);
    if (kq == 0)
      p.out[(size_t)(g*GB + row)*(T_*9) + (size_t)t*9 + d0 + d] = acc + bfc_l[d0 + d];
  }
}

// LDS layout (dynamic):
#define OFF_W1P   0u        // [48][64]  bf16 -> 6144 B
#define OFF_W2P   6144u     // [48][64]
#define OFF_WHH   12288u    // 4 x [48][128] -> 49152 B
#define OFF_W3    61440u    // [48][256] -> 24576 B
#define OFF_W4    86016u    // [48][256]
#define OFF_WFC   110592u   // 9x128 f32 -> 4608 B
#define OFF_BFC   115200u   // 9 f32 (pad to 64)
#define OFF_XA    115264u   // [32][32] bf16 -> 2048 B
#define SMEM_BYTES 117312u

__global__ __launch_bounds__(256, 1) void gru_main(Params p) {
  extern __shared__ __align__(16) unsigned char smem[];
  unsigned short* w1p = (unsigned short*)(smem + OFF_W1P);
  unsigned short* w2p = (unsigned short*)(smem + OFF_W2P);
  unsigned short* whhl0 = (unsigned short*)(smem + OFF_WHH);
  unsigned short* w3 = (unsigned short*)(smem + OFF_W3);
  unsigned short* w4 = (unsigned short*)(smem + OFF_W4);
  float (*wfc_l)[H_] = (float(*)[H_])(smem + OFF_WFC);
  float* bfc_l = (float*)(smem + OFF_BFC);
  unsigned short* xa = (unsigned short*)(smem + OFF_XA);   // [32 rows][32 cols]

  const int tid = threadIdx.x;
  const int lane = tid & 63;
  const int wid = tid >> 6;          // 0..3
  const int nlo = lane & 15;
  const int khi = lane >> 4;
  const int g = blockIdx.x >> 3;     // batch group
  const int s = blockIdx.x & 7;      // hidden slice (== XCD under round-robin heuristic)
  const int colg = s*SC + nlo;
  const int cA = wid >> 1;           // stage-A cell: 0 -> cell1, 1 -> cell2
  const int cB = 2 + (wid >> 1);     // stage-B/C cell: 2 (waves 0,1) / 3 (waves 2,3)
  const int m = wid & 1;             // batch M-tile

  // ---- prologue: weights -> LDS (swizzled bf16) ----
  load_w<64, 24>(w1p, p.wih[0], s, tid);
  load_w<64, 25>(w2p, p.wih[1], s, tid);       // col 24 = lai weight
#pragma unroll
  for (int c = 0; c < 4; ++c) load_w<128, 128>(whhl0 + c*48*128, p.whh[c], s, tid);
  load_w<256, 256>(w3, p.wih[2], s, tid);
  load_w<256, 256>(w4, p.wih[3], s, tid);
  // FC weights fp32 -> LDS
  for (int i = tid; i < 9*H_; i += 256) {
    int rw = i >> 7, k = i & 127;
    const float* src; int lr;
    if (rw == 0)      { src = p.wfc[0]; lr = 0; }
    else if (rw < 4)  { src = p.wfc[1]; lr = rw - 1; }
    else if (rw < 7)  { src = p.wfc[2]; lr = rw - 4; }
    else              { src = p.wfc[3]; lr = rw - 7; }
    wfc_l[rw][k] = src[lr*H_ + k];
  }
  if (tid < 9)
    bfc_l[tid] = (tid == 0) ? p.bfc[0][0]
               : (tid < 4)  ? p.bfc[1][tid-1]
               : (tid < 7)  ? p.bfc[2][tid-4] : p.bfc[3][tid-7];
  // xa for t=0 (lai = 0)
  for (int i = tid; i < GB*32; i += 256) {
    int row = i >> 5, col = i & 31;
    unsigned short v = 0;
    if (col < 24) v = f2b(p.x[(size_t)(g*GB + row)*(T_*D_) + col]);
    xa[row*32 + col] = v;
  }
  // biases (per output column)
  float brz[4][2], bi_[4], bh_[4];
#pragma unroll
  for (int c = 0; c < 4; ++c) {
    brz[c][0] = p.bih[c][colg] + p.bhh[c][colg];
    brz[c][1] = p.bih[c][H_ + colg] + p.bhh[c][H_ + colg];
    bi_[c] = p.bih[c][2*H_ + colg];
    bh_[c] = p.bhh[c][2*H_ + colg];
  }
  // fp32 register h-carry: hA -> stage-A cell tile, hB -> stage-B/C cell tile
  float hA[4] = {0.f,0.f,0.f,0.f}, hB[4] = {0.f,0.f,0.f,0.f};
  __syncthreads();

  for (int t = 0; t < T_; ++t) {
    const int pbo = t & 1, pbn = pbo ^ 1;

    // ---- stage A: cells 1 & 2 (all 4 waves) ----
    {
      const unsigned short* Wb = cA ? w2p : w1p;
      const unsigned short* Wh = whhl0 + cA*48*128;
      const int k0 = khi*8;
      bf16x8 ax = *(const bf16x8*)&xa[(m*16 + nlo)*32 + k0];
      f32x4 R = {0,0,0,0}, Z = {0,0,0,0}, I = {0,0,0,0}, Hh = {0,0,0,0};
      R = MFMA(ax, wfrag(Wb, nlo,      k0, 64), R);
      Z = MFMA(ax, wfrag(Wb, 16 + nlo, k0, 64), Z);
      I = MFMA(ax, wfrag(Wb, 32 + nlo, k0, 64), I);
      const int hrow = g*GB + m*16 + nlo;
#pragma unroll
      for (int kc = 0; kc < 4; ++kc) {
        int k = kc*32 + k0;
        bf16x8 ah = *(const bf16x8*)&g_hx[pbo][cA][hrow][k];
        R  = MFMA(ah, wfrag(Wh, nlo,      k, 128), R);
        Z  = MFMA(ah, wfrag(Wh, 16 + nlo, k, 128), Z);
        Hh = MFMA(ah, wfrag(Wh, 32 + nlo, k, 128), Hh);
      }
      finish_cell(p, R, Z, I, Hh, cA, hA, brz[cA][0], brz[cA][1], bi_[cA], bh_[cA],
                  pbn, g, m, khi, colg, t);
    }
    group_sync(g, 0, (unsigned)(NS*(t+1)));

    // ---- stage B: cell 3 (waves 0,1); FC o1/o2 on waves 2,3 of slices 0/1 ----
    if (cB == 2) {
      const unsigned short* Wh = whhl0 + 2*48*128;
      const int k0 = khi*8;
      const int hrow = g*GB + m*16 + nlo;
      f32x4 R = {0,0,0,0}, Z = {0,0,0,0}, I = {0,0,0,0}, Hh = {0,0,0,0};
#pragma unroll
      for (int kc = 0; kc < 4; ++kc) {
        int k = kc*32 + k0;
        bf16x8 a = *(const bf16x8*)&g_hx[pbn][0][hrow][k];   // h1 new
        R = MFMA(a, wfrag(w3, nlo,      k, 256), R);
        Z = MFMA(a, wfrag(w3, 16 + nlo, k, 256), Z);
        I = MFMA(a, wfrag(w3, 32 + nlo, k, 256), I);
      }
#pragma unroll
      for (int kc = 0; kc < 4; ++kc) {
        int k = kc*32 + k0, kw = 128 + k;
        bf16x8 a = *(const bf16x8*)&g_hx[pbn][1][hrow][k];   // h2 new
        R = MFMA(a, wfrag(w3, nlo,      kw, 256), R);
        Z = MFMA(a, wfrag(w3, 16 + nlo, kw, 256), Z);
        I = MFMA(a, wfrag(w3, 32 + nlo, kw, 256), I);
      }
#pragma unroll
      for (int kc = 0; kc < 4; ++kc) {
        int k = kc*32 + k0;
        bf16x8 a = *(const bf16x8*)&g_hx[pbo][2][hrow][k];   // h3 old
        R  = MFMA(a, wfrag(Wh, nlo,      k, 128), R);
        Z  = MFMA(a, wfrag(Wh, 16 + nlo, k, 128), Z);
        Hh = MFMA(a, wfrag(Wh, 32 + nlo, k, 128), Hh);
      }
      finish_cell(p, R, Z, I, Hh, 2, hB, brz[2][0], brz[2][1], bi_[2], bh_[2],
                  pbn, g, m, khi, colg, t);
    } else if (s == 0) {
      fc_dots(p, wfc_l, bfc_l, 0, 0, 1, g, pbn, t, wid, lane, 2);   // o1 from h1
    } else if (s == 1) {
      fc_dots(p, wfc_l, bfc_l, 1, 1, 3, g, pbn, t, wid, lane, 2);   // o2 from h2
    }
    group_sync(g, 1, (unsigned)(NS*(t+1)));

    // ---- stage C: cell 4 (waves 2,3); FC o3 on waves 0,1 of slice 2 ----
    if (cB == 3) {
      const unsigned short* Wh = whhl0 + 3*48*128;
      const int k0 = khi*8;
      const int hrow = g*GB + m*16 + nlo;
      f32x4 R = {0,0,0,0}, Z = {0,0,0,0}, I = {0,0,0,0}, Hh = {0,0,0,0};
#pragma unroll
      for (int kc = 0; kc < 4; ++kc) {
        int k = kc*32 + k0;
        bf16x8 a = *(const bf16x8*)&g_hx[pbn][0][hrow][k];   // h1 new
        R = MFMA(a, wfrag(w4, nlo,      k, 256), R);
        Z = MFMA(a, wfrag(w4, 16 + nlo, k, 256), Z);
        I = MFMA(a, wfrag(w4, 32 + nlo, k, 256), I);
      }
#pragma unroll
      for (int kc = 0; kc < 4; ++kc) {
        int k = kc*32 + k0, kw = 128 + k;
        bf16x8 a = *(const bf16x8*)&g_hx[pbn][2][hrow][k];   // h3 new
        R = MFMA(a, wfrag(w4, nlo,      kw, 256), R);
        Z = MFMA(a, wfrag(w4, 16 + nlo, kw, 256), Z);
        I = MFMA(a, wfrag(w4, 32 + nlo, kw, 256), I);
      }
#pragma unroll
      for (int kc = 0; kc < 4; ++kc) {
        int k = kc*32 + k0;
        bf16x8 a = *(const bf16x8*)&g_hx[pbo][3][hrow][k];   // h4 old
        R  = MFMA(a, wfrag(Wh, nlo,      k, 128), R);
        Z  = MFMA(a, wfrag(Wh, 16 + nlo, k, 128), Z);
        Hh = MFMA(a, wfrag(Wh, 32 + nlo, k, 128), Hh);
      }
      finish_cell(p, R, Z, I, Hh, 3, hB, brz[3][0], brz[3][1], bi_[3], bh_[3],
                  pbn, g, m, khi, colg, t);
    } else if (s == 2) {
      fc_dots(p, wfc_l, bfc_l, 2, 4, 3, g, pbn, t, wid, lane, 0);   // o3 from h3
    }
    group_sync(g, 2, (unsigned)(NS*(t+1)));

    // ---- epilogue: o4 + lai (wave 0, replicated per block); x staging (waves 1-3) ----
    if (wid == 0) {
      int row = lane & 31, half = lane >> 5;
      const unsigned short* hb = &g_hx[pbn][3][g*GB + row][half*64];
      float a0 = 0.f, a1 = 0.f;
#pragma unroll
      for (int j = 0; j < 8; ++j) {
        bf16x8 v = *(const bf16x8*)(hb + j*8);
#pragma unroll
        for (int e = 0; e < 8; ++e) {
          float hval = b2f((unsigned short)v[e]);
          a0 += hval * wfc_l[7][half*64 + j*8 + e];
          a1 += hval * wfc_l[8][half*64 + j*8 + e];
        }
      }
      a0 += __shfl_xor(a0, 32);
      a1 += __shfl_xor(a1, 32);
      if (half == 0) {
        float o40 = a0 + bfc_l[7];
        xa[row*32 + 24] = f2b(o40);          // lai for next step
        if (s == 3) {
          size_t ob = (size_t)(g*GB + row)*(T_*9) + (size_t)t*9;
          p.out[ob + 7] = o40;
          p.out[ob + 8] = a1 + bfc_l[8];
        }
      }
    } else if (t + 1 < T_) {
      for (int i = tid - 64; i < GB*32; i += 192) {
        int row = i >> 5, col = i & 31;
        if (col == 24) continue;
        unsigned short v = 0;
        if (col < 24)
          v = f2b(p.x[(size_t)(g*GB + row)*(T_*D_) + (size_t)(t+1)*D_ + col]);
        xa[row*32 + col] = v;
      }
    }
    __syncthreads();
  }

  // ---- final hidden states from fp32 register carry ----
#pragma unroll
  for (int q = 0; q < 4; ++q) {
    int row = g*GB + m*16 + khi*4 + q;
    p.hf[cA][(size_t)row*H_ + colg] = hA[q];
    p.hf[cB][(size_t)row*H_ + colg] = hB[q];
  }
}

// ---------------- launcher ----------------
extern "C" void kernel_launch(void* const* d_in, const int* in_sizes, int n_in,
                              void* d_out, int out_size, void* d_ws, size_t ws_size,
                              hipStream_t stream) {
  (void)in_sizes; (void)n_in; (void)d_ws; (void)ws_size; (void)out_size;
  Params p;
  p.x = (const float*)d_in[0];
  for (int c = 0; c < 4; ++c) {
    p.wih[c] = (const float*)d_in[1 + 6*c];
    p.whh[c] = (const float*)d_in[2 + 6*c];
    p.bih[c] = (const float*)d_in[3 + 6*c];
    p.bhh[c] = (const float*)d_in[4 + 6*c];
    p.wfc[c] = (const float*)d_in[5 + 6*c];
    p.bfc[c] = (const float*)d_in[6 + 6*c];
  }
  float* out = (float*)d_out;
  p.out = out;
  const size_t HF_OFF = (size_t)B_ * T_ * 9;
  const size_t HT_OFF = HF_OFF + 4ull * B_ * H_;
  const size_t HT_SZ = (size_t)B_ * T_ * H_;
  for (int c = 0; c < 4; ++c) {
    p.hf[c] = out + HF_OFF + (size_t)c * B_ * H_;
    p.hT[c] = out + HT_OFF + (size_t)c * HT_SZ;
  }

  // allow >64KB dynamic LDS (idempotent; safe outside stream ops)
  static bool attr_done = false;
  hipFuncSetAttribute(reinterpret_cast<const void*>(gru_main),
                      hipFuncAttributeMaxDynamicSharedMemorySize, (int)SMEM_BYTES);
  (void)attr_done;

  init_exchange<<<512, 256, 0, stream>>>();
  gru_main<<<NG * NS, 256, SMEM_BYTES, stream>>>(p);
}

// Round 3
// 13158.841 us; speedup vs baseline: 1.1336x; 1.1336x over previous
//
#include <hip/hip_runtime.h>
#include <hip/hip_bf16.h>

// ---------------- problem constants ----------------
#define B_   1024
#define T_   365
#define D_   24
#define H_   128

// bf16 weight arena layout (ushort element offsets)
#define WIH1P_OFF 0         // [384][32]  (24 cols + zero pad)
#define WIH2P_OFF 12288     // [384][32]  (24 x cols, col24 = lai weight, pad)
#define WHH_OFF   24576     // 4 x [384][128]
#define WIH3_OFF  221184    // [384][256]
#define WIH4_OFF  319488    // [384][256]
#define WS_ELEMS  417792

typedef __attribute__((ext_vector_type(8))) short bf16x8;
typedef __attribute__((ext_vector_type(4))) float f32x4;

__device__ __align__(16) unsigned short g_ws[WS_ELEMS];

#define MFMA(a, b, c) __builtin_amdgcn_mfma_f32_16x16x32_bf16((a), (b), (c), 0, 0, 0)
#define SB() __builtin_amdgcn_sched_barrier(0)

__device__ __forceinline__ bf16x8 ldw(const unsigned short* p) {
  return *(const bf16x8*)p;
}
__device__ __forceinline__ unsigned short f2b(float f) {
  union { __hip_bfloat16 h; unsigned short u; } cv;
  cv.h = __float2bfloat16(f);   // RNE
  return cv.u;
}
__device__ __forceinline__ float b2f(unsigned short u) {
  union { float f; unsigned int u32; } cv;
  cv.u32 = ((unsigned int)u) << 16;
  return cv.f;
}
__device__ __forceinline__ float sigmoidf_(float x) { return 1.f / (1.f + __expf(-x)); }
__device__ __forceinline__ float tanhf_(float x) {
  float e = __expf(2.f * x);
  return 1.f - 2.f / (e + 1.f);   // handles +-inf limits correctly
}

// ---------------- prologue: fp32 -> padded bf16 weights ----------------
__global__ void prep_weights(const float* wih1, const float* wih2,
                             const float* whh1, const float* whh2,
                             const float* whh3, const float* whh4,
                             const float* wih3, const float* wih4) {
  int i = blockIdx.x * blockDim.x + threadIdx.x;
  if (i >= WS_ELEMS) return;
  float v;
  if (i < 12288) {                       // Wih1 padded [384][32]
    int r = i >> 5, c = i & 31;
    v = (c < 24) ? wih1[r * 24 + c] : 0.f;
  } else if (i < 24576) {                // Wih2 padded [384][32] (col 24 = lai)
    int j = i - 12288;
    int r = j >> 5, c = j & 31;
    v = (c < 25) ? wih2[r * 25 + c] : 0.f;
  } else if (i < 221184) {               // Whh1..4 [384][128]
    int j = i - 24576;
    if      (j < 49152)  v = whh1[j];
    else if (j < 98304)  v = whh2[j - 49152];
    else if (j < 147456) v = whh3[j - 98304];
    else                 v = whh4[j - 147456];
  } else if (i < 319488) {               // Wih3 [384][256]
    v = wih3[i - 221184];
  } else {                               // Wih4 [384][256]
    v = wih4[i - 319488];
  }
  g_ws[i] = f2b(v);
}

// ---------------- main persistent kernel ----------------
struct GruParams {
  const float* x;
  const float* bih[4];
  const float* bhh[4];
  const float* wfc[4];
  const float* bfc[4];
  float* out;        // [B][T][9]
  float* hf[4];      // [B][128] final states
  float* hT[4];      // [B][T][128]
};

__global__ __launch_bounds__(512, 2) void gru_main(GruParams p) {
  // hfrag[buf][cell][kg][m][e] : bf16 h, chunk (kg,m) = 8 contiguous k for MFMA frags
  __shared__ unsigned short hfrag[2][4][16][16][8];   // 32 KB
  __shared__ unsigned short xa[4][16][8];             // [kg][m][e], 1 KB

  const int tid  = threadIdx.x;
  const int lane = tid & 63;
  const int wid  = tid >> 6;       // 0..7
  const int nlo  = lane & 15;
  const int khi  = lane >> 4;      // 0..3
  const int nh   = wid * 16 + nlo; // hidden column this lane owns
  const int b0   = blockIdx.x * 16;
  const int k8   = khi * 8;

  for (int i = tid; i < 2 * 4 * 16 * 16 * 8; i += 512) ((unsigned short*)hfrag)[i] = 0;
  // stage x for t=0 (col24 = lai = 0; cols 25..31 stay 0 forever)
  {
    int row = tid >> 5, col = tid & 31;
    float v = (col < 24) ? p.x[(size_t)(b0 + row) * (T_ * D_) + col] : 0.f;
    xa[col >> 3][row][col & 7] = f2b(v);
  }

  // fp32 hidden-state carry: hreg[c][q] == h_c[m = khi*4+q][nh]
  float hreg[4][4];
#pragma unroll
  for (int c = 0; c < 4; ++c)
#pragma unroll
    for (int q = 0; q < 4; ++q) hreg[c][q] = 0.f;

  // hoisted biases
  float brz[4][2], bin[4], bhn[4];
#pragma unroll
  for (int c = 0; c < 4; ++c) {
    brz[c][0] = p.bih[c][nh] + p.bhh[c][nh];
    brz[c][1] = p.bih[c][128 + nh] + p.bhh[c][128 + nh];
    bin[c]    = p.bih[c][256 + nh];
    bhn[c]    = p.bhh[c][256 + nh];
  }

  // base pointers: all fragment offsets become compile-time immediates
  const unsigned short* pw1 = g_ws + WIH1P_OFF + nh * 32  + k8;
  const unsigned short* pw2 = g_ws + WIH2P_OFF + nh * 32  + k8;
  const unsigned short* pwh = g_ws + WHH_OFF   + nh * 128 + k8;
  const unsigned short* pw3 = g_ws + WIH3_OFF  + nh * 256 + k8;
  const unsigned short* pw4 = g_ws + WIH4_OFF  + nh * 256 + k8;

  // FC assignment: 144 threads = 16 rows x 9 outputs
  const bool fc_on = (tid < 144);
  const int foi = tid % 9;
  int frow = 0, fcell = 0;
  const float4* fw4 = nullptr;
  float fb = 0.f;
  if (fc_on) {
    frow = tid / 9;
    const float* fw;
    if (foi == 0)     { fcell = 0; fw = p.wfc[0];                   fb = p.bfc[0][0]; }
    else if (foi < 4) { fcell = 1; fw = p.wfc[1] + (foi - 1) * 128; fb = p.bfc[1][foi - 1]; }
    else if (foi < 7) { fcell = 2; fw = p.wfc[2] + (foi - 4) * 128; fb = p.bfc[2][foi - 4]; }
    else              { fcell = 3; fw = p.wfc[3] + (foi - 7) * 128; fb = p.bfc[3][foi - 7]; }
    fw4 = (const float4*)fw;
  }

  __syncthreads();

  for (int t = 0; t < T_; ++t) {
    const int ib = t & 1, ob = ib ^ 1;

    // ================= stage A: cells 1 & 2 =================
    {
      bf16x8 ax = ldw(&xa[khi][nlo][0]);
      bf16x8 a1[4], a2[4];
#pragma unroll
      for (int kc = 0; kc < 4; ++kc) {
        a1[kc] = ldw(&hfrag[ib][0][kc * 4 + khi][nlo][0]);
        a2[kc] = ldw(&hfrag[ib][1][kc * 4 + khi][nlo][0]);
      }
      bf16x8 c0[12], c1[12], c2[6];
#pragma unroll
      for (int g = 0; g < 3; ++g) { c0[g] = ldw(pw1 + g * 4096); c0[3 + g] = ldw(pw2 + g * 4096); }
#pragma unroll
      for (int kc = 0; kc < 2; ++kc)
#pragma unroll
        for (int g = 0; g < 3; ++g) c0[6 + kc * 3 + g] = ldw(pwh + g * 16384 + kc * 32);
#pragma unroll
      for (int kc = 2; kc < 4; ++kc)
#pragma unroll
        for (int g = 0; g < 3; ++g) c1[(kc - 2) * 3 + g] = ldw(pwh + g * 16384 + kc * 32);
#pragma unroll
      for (int kc = 0; kc < 2; ++kc)
#pragma unroll
        for (int g = 0; g < 3; ++g) c1[6 + kc * 3 + g] = ldw(pwh + 49152 + g * 16384 + kc * 32);
      SB();
      f32x4 R1 = {0.f,0.f,0.f,0.f}, Z1 = R1, I1 = R1, Hh1 = R1;
      f32x4 R2 = R1, Z2 = R1, I2 = R1, Hh2 = R1;
      R1 = MFMA(ax, c0[0], R1); Z1 = MFMA(ax, c0[1], Z1); I1 = MFMA(ax, c0[2], I1);
      R2 = MFMA(ax, c0[3], R2); Z2 = MFMA(ax, c0[4], Z2); I2 = MFMA(ax, c0[5], I2);
#pragma unroll
      for (int kc = 0; kc < 2; ++kc) {
        R1  = MFMA(a1[kc], c0[6 + kc * 3],     R1);
        Z1  = MFMA(a1[kc], c0[6 + kc * 3 + 1], Z1);
        Hh1 = MFMA(a1[kc], c0[6 + kc * 3 + 2], Hh1);
      }
#pragma unroll
      for (int kc = 2; kc < 4; ++kc)
#pragma unroll
        for (int g = 0; g < 3; ++g) c2[(kc - 2) * 3 + g] = ldw(pwh + 49152 + g * 16384 + kc * 32);
      SB();
#pragma unroll
      for (int kc = 2; kc < 4; ++kc) {
        R1  = MFMA(a1[kc], c1[(kc - 2) * 3],     R1);
        Z1  = MFMA(a1[kc], c1[(kc - 2) * 3 + 1], Z1);
        Hh1 = MFMA(a1[kc], c1[(kc - 2) * 3 + 2], Hh1);
      }
#pragma unroll
      for (int kc = 0; kc < 2; ++kc) {
        R2  = MFMA(a2[kc], c1[6 + kc * 3],     R2);
        Z2  = MFMA(a2[kc], c1[6 + kc * 3 + 1], Z2);
        Hh2 = MFMA(a2[kc], c1[6 + kc * 3 + 2], Hh2);
      }
#pragma unroll
      for (int kc = 2; kc < 4; ++kc) {
        R2  = MFMA(a2[kc], c2[(kc - 2) * 3],     R2);
        Z2  = MFMA(a2[kc], c2[(kc - 2) * 3 + 1], Z2);
        Hh2 = MFMA(a2[kc], c2[(kc - 2) * 3 + 2], Hh2);
      }
#pragma unroll
      for (int q = 0; q < 4; ++q) {
        int m = khi * 4 + q;
        {
          float r = sigmoidf_(R1[q] + brz[0][0]);
          float z = sigmoidf_(Z1[q] + brz[0][1]);
          float n = tanhf_(I1[q] + bin[0] + r * (Hh1[q] + bhn[0]));
          float hnew = (1.f - z) * n + z * hreg[0][q];
          hreg[0][q] = hnew;
          hfrag[ob][0][nh >> 3][m][nh & 7] = f2b(hnew);
        }
        {
          float r = sigmoidf_(R2[q] + brz[1][0]);
          float z = sigmoidf_(Z2[q] + brz[1][1]);
          float n = tanhf_(I2[q] + bin[1] + r * (Hh2[q] + bhn[1]));
          float hnew = (1.f - z) * n + z * hreg[1][q];
          hreg[1][q] = hnew;
          hfrag[ob][1][nh >> 3][m][nh & 7] = f2b(hnew);
        }
      }
    }
    __syncthreads();

    // ================= stage B: cell 3 =================
    bf16x8 h1n[4];   // kept live for stage C
    {
      bf16x8 h2n[4], a3[4];
#pragma unroll
      for (int kc = 0; kc < 4; ++kc) {
        h1n[kc] = ldw(&hfrag[ob][0][kc * 4 + khi][nlo][0]);
        h2n[kc] = ldw(&hfrag[ob][1][kc * 4 + khi][nlo][0]);
        a3[kc]  = ldw(&hfrag[ib][2][kc * 4 + khi][nlo][0]);
      }
      bf16x8 c0[12], c1[12], c2[12];
#pragma unroll
      for (int kc = 0; kc < 4; ++kc)
#pragma unroll
        for (int g = 0; g < 3; ++g) c0[kc * 3 + g] = ldw(pw3 + g * 32768 + kc * 32);
#pragma unroll
      for (int kc = 0; kc < 4; ++kc)
#pragma unroll
        for (int g = 0; g < 3; ++g) c1[kc * 3 + g] = ldw(pw3 + 128 + g * 32768 + kc * 32);
      SB();
      f32x4 R = {0.f,0.f,0.f,0.f}, Z = R, I = R, Hh = R;
#pragma unroll
      for (int kc = 0; kc < 4; ++kc) {
        R = MFMA(h1n[kc], c0[kc * 3],     R);
        Z = MFMA(h1n[kc], c0[kc * 3 + 1], Z);
        I = MFMA(h1n[kc], c0[kc * 3 + 2], I);
      }
#pragma unroll
      for (int kc = 0; kc < 4; ++kc)
#pragma unroll
        for (int g = 0; g < 3; ++g) c2[kc * 3 + g] = ldw(pwh + 2 * 49152 + g * 16384 + kc * 32);
      SB();
#pragma unroll
      for (int kc = 0; kc < 4; ++kc) {
        R = MFMA(h2n[kc], c1[kc * 3],     R);
        Z = MFMA(h2n[kc], c1[kc * 3 + 1], Z);
        I = MFMA(h2n[kc], c1[kc * 3 + 2], I);
      }
#pragma unroll
      for (int kc = 0; kc < 4; ++kc) {
        R  = MFMA(a3[kc], c2[kc * 3],     R);
        Z  = MFMA(a3[kc], c2[kc * 3 + 1], Z);
        Hh = MFMA(a3[kc], c2[kc * 3 + 2], Hh);
      }
#pragma unroll
      for (int q = 0; q < 4; ++q) {
        int m = khi * 4 + q;
        float r = sigmoidf_(R[q] + brz[2][0]);
        float z = sigmoidf_(Z[q] + brz[2][1]);
        float n = tanhf_(I[q] + bin[2] + r * (Hh[q] + bhn[2]));
        float hnew = (1.f - z) * n + z * hreg[2][q];
        hreg[2][q] = hnew;
        hfrag[ob][2][nh >> 3][m][nh & 7] = f2b(hnew);
      }
    }
    __syncthreads();

    // ================= stage C: cell 4 =================
    {
      bf16x8 h3n[4], a4[4];
#pragma unroll
      for (int kc = 0; kc < 4; ++kc) {
        h3n[kc] = ldw(&hfrag[ob][2][kc * 4 + khi][nlo][0]);
        a4[kc]  = ldw(&hfrag[ib][3][kc * 4 + khi][nlo][0]);
      }
      bf16x8 c0[12], c1[12], c2[12];
#pragma unroll
      for (int kc = 0; kc < 4; ++kc)
#pragma unroll
        for (int g = 0; g < 3; ++g) c0[kc * 3 + g] = ldw(pw4 + g * 32768 + kc * 32);
#pragma unroll
      for (int kc = 0; kc < 4; ++kc)
#pragma unroll
        for (int g = 0; g < 3; ++g) c1[kc * 3 + g] = ldw(pw4 + 128 + g * 32768 + kc * 32);
      SB();
      f32x4 R = {0.f,0.f,0.f,0.f}, Z = R, I = R, Hh = R;
#pragma unroll
      for (int kc = 0; kc < 4; ++kc) {
        R = MFMA(h1n[kc], c0[kc * 3],     R);
        Z = MFMA(h1n[kc], c0[kc * 3 + 1], Z);
        I = MFMA(h1n[kc], c0[kc * 3 + 2], I);
      }
#pragma unroll
      for (int kc = 0; kc < 4; ++kc)
#pragma unroll
        for (int g = 0; g < 3; ++g) c2[kc * 3 + g] = ldw(pwh + 3 * 49152 + g * 16384 + kc * 32);
      SB();
#pragma unroll
      for (int kc = 0; kc < 4; ++kc) {
        R = MFMA(h3n[kc], c1[kc * 3],     R);
        Z = MFMA(h3n[kc], c1[kc * 3 + 1], Z);
        I = MFMA(h3n[kc], c1[kc * 3 + 2], I);
      }
#pragma unroll
      for (int kc = 0; kc < 4; ++kc) {
        R  = MFMA(a4[kc], c2[kc * 3],     R);
        Z  = MFMA(a4[kc], c2[kc * 3 + 1], Z);
        Hh = MFMA(a4[kc], c2[kc * 3 + 2], Hh);
      }
#pragma unroll
      for (int q = 0; q < 4; ++q) {
        int m = khi * 4 + q;
        float r = sigmoidf_(R[q] + brz[3][0]);
        float z = sigmoidf_(Z[q] + brz[3][1]);
        float n = tanhf_(I[q] + bin[3] + r * (Hh[q] + bhn[3]));
        float hnew = (1.f - z) * n + z * hreg[3][q];
        hreg[3][q] = hnew;
        hfrag[ob][3][nh >> 3][m][nh & 7] = f2b(hnew);
      }
    }
    __syncthreads();

    // ========= FC heads + hT stores + x staging (one phase) =========
    // all threads: hT stores for this step's h (fp32 from registers)
#pragma unroll
    for (int c = 0; c < 4; ++c)
#pragma unroll
      for (int q = 0; q < 4; ++q) {
        int m = khi * 4 + q;
        p.hT[c][(size_t)(b0 + m) * (T_ * H_) + (size_t)t * H_ + nh] = hreg[c][q];
      }
    if (fc_on) {
      const unsigned short* hb = &hfrag[ob][fcell][0][frow][0];
      float acc = fb;
#pragma unroll
      for (int kg = 0; kg < 16; ++kg) {
        bf16x8 hv = *(const bf16x8*)(hb + kg * 128);
        float4 wA = fw4[kg * 2], wB = fw4[kg * 2 + 1];
        acc += b2f((unsigned short)hv[0]) * wA.x + b2f((unsigned short)hv[1]) * wA.y +
               b2f((unsigned short)hv[2]) * wA.z + b2f((unsigned short)hv[3]) * wA.w +
               b2f((unsigned short)hv[4]) * wB.x + b2f((unsigned short)hv[5]) * wB.y +
               b2f((unsigned short)hv[6]) * wB.z + b2f((unsigned short)hv[7]) * wB.w;
      }
      p.out[(size_t)(b0 + frow) * (T_ * 9) + t * 9 + foi] = acc;
      if (foi == 7) xa[3][frow][0] = f2b(acc);   // lai for next step (o4 col 0)
    } else if (tid >= 256 && t + 1 < T_) {
      // waves 4-7: stage x_{t+1} cols 0..23 (col 24 written by FC; 25..31 stay 0)
      for (int i = tid - 256; i < 16 * 24; i += 256) {
        int row = i / 24, col = i % 24;
        xa[col >> 3][row][col & 7] =
            f2b(p.x[(size_t)(b0 + row) * (T_ * D_) + (size_t)(t + 1) * D_ + col]);
      }
    }
    __syncthreads();
  }

  // ---- final hidden states (fp32 from register carry) ----
#pragma unroll
  for (int c = 0; c < 4; ++c)
#pragma unroll
    for (int q = 0; q < 4; ++q)
      p.hf[c][(size_t)(b0 + khi * 4 + q) * H_ + nh] = hreg[c][q];
}

// ---------------- launcher ----------------
extern "C" void kernel_launch(void* const* d_in, const int* in_sizes, int n_in,
                              void* d_out, int out_size, void* d_ws, size_t ws_size,
                              hipStream_t stream) {
  (void)in_sizes; (void)n_in; (void)d_ws; (void)ws_size; (void)out_size;
  const float* x    = (const float*)d_in[0];
  const float* wih1 = (const float*)d_in[1];
  const float* whh1 = (const float*)d_in[2];
  const float* wih2 = (const float*)d_in[7];
  const float* whh2 = (const float*)d_in[8];
  const float* wih3 = (const float*)d_in[13];
  const float* whh3 = (const float*)d_in[14];
  const float* wih4 = (const float*)d_in[19];
  const float* whh4 = (const float*)d_in[20];

  prep_weights<<<(WS_ELEMS + 255) / 256, 256, 0, stream>>>(wih1, wih2, whh1, whh2,
                                                           whh3, whh4, wih3, wih4);

  GruParams p;
  p.x = x;
  for (int c = 0; c < 4; ++c) {
    p.bih[c] = (const float*)d_in[3 + 6 * c];
    p.bhh[c] = (const float*)d_in[4 + 6 * c];
    p.wfc[c] = (const float*)d_in[5 + 6 * c];
    p.bfc[c] = (const float*)d_in[6 + 6 * c];
  }
  float* out = (float*)d_out;
  p.out = out;                                    // B*T*9 = 3,363,840
  const size_t HF_OFF = (size_t)B_ * T_ * 9;      // 3,363,840
  const size_t HT_OFF = HF_OFF + 4ull * B_ * H_;  // 3,888,128
  const size_t HT_SZ  = (size_t)B_ * T_ * H_;     // 47,841,280
  for (int c = 0; c < 4; ++c) {
    p.hf[c] = out + HF_OFF + (size_t)c * B_ * H_;
    p.hT[c] = out + HT_OFF + (size_t)c * HT_SZ;
  }
  gru_main<<<64, 512, 0, stream>>>(p);
}